// Round 4
// baseline (227.451 us; speedup 1.0000x reference)
//
#include <hip/hip_runtime.h>
#include <hip/hip_bf16.h>
#include <math.h>

// Problem constants (fixed by setup_inputs)
#define BATCH 16
#define LEN   262144
#define HOP   256
#define PADW  512          // n_fft/2
#define NFREQ 513          // rfft bins
#define NFRM  1025         // frames
#define NPT   65           // time patches
#define NPF   33           // freq patches
#define NPATCH 2145        // 33*65
#define TOPK  643          // int(2145*0.3)
#define EPSV  1e-8f

// LDS bank-conflict swizzle: float2 element i lives at phys i^((i>>4)&15).
#define SW(i) ((i) ^ (((i) >> 4) & 15))

__device__ __forceinline__ int reflect_idx(int g) {
    g = (g < 0) ? -g : g;
    g = (g >= LEN) ? (2 * LEN - 2 - g) : g;
    return g;
}

// load packed frame: xs[i] = re_src[refl(startRe+i)] + i*im_src[refl(startIm+i)]
__device__ __forceinline__ void load_pack(float2* xs,
    const float* __restrict__ re_src, const float* __restrict__ im_src,
    int startRe, int startIm, int tid)
{
    #pragma unroll
    for (int m = 0; m < 4; ++m) {
        const int i = tid + 256 * m;
        xs[SW(i)] = make_float2(re_src[reflect_idx(startRe + i)],
                                im_src[reflect_idx(startIm + i)]);
    }
    __syncthreads();
}

// 1024-pt radix-4 DIF complex FFT. Natural input, base-4 digit-reversed output.
// Only w1 read from table (exponent < 256 always); w2=w1^2, w3=w2*w1.
__device__ __forceinline__ void fft1024(float2* xs, const float2* tw, int tid) {
    #pragma unroll
    for (int s = 0; s < 5; ++s) {
        const int lenlog = 10 - 2 * s;
        const int q      = 1 << (lenlog - 2);
        const int pos    = tid & (q - 1);
        const int blk    = tid >> (lenlog - 2);
        const int i0     = (blk << lenlog) + pos;

        float2 a  = xs[SW(i0)];
        float2 bb = xs[SW(i0 + q)];
        float2 c  = xs[SW(i0 + 2 * q)];
        float2 d  = xs[SW(i0 + 3 * q)];

        const float t0x = a.x + c.x,  t0y = a.y + c.y;
        const float t1x = a.x - c.x,  t1y = a.y - c.y;
        const float t2x = bb.x + d.x, t2y = bb.y + d.y;
        const float t3x = bb.x - d.x, t3y = bb.y - d.y;

        // w4 = -i butterfly
        const float y0x = t0x + t2x, y0y = t0y + t2y;
        const float y1x = t1x + t3y, y1y = t1y - t3x;
        const float y2x = t0x - t2x, y2y = t0y - t2y;
        const float y3x = t1x - t3y, y3y = t1y + t3x;

        const int e = pos << (2 * s);           // always < 256
        const float2 w1 = tw[SW(e)];
        const float2 w2 = make_float2(w1.x * w1.x - w1.y * w1.y, 2.0f * w1.x * w1.y);
        const float2 w3 = make_float2(w2.x * w1.x - w2.y * w1.y, w2.x * w1.y + w2.y * w1.x);

        xs[SW(i0)]         = make_float2(y0x, y0y);
        xs[SW(i0 + q)]     = make_float2(y1x * w1.x - y1y * w1.y, y1x * w1.y + y1y * w1.x);
        xs[SW(i0 + 2 * q)] = make_float2(y2x * w2.x - y2y * w2.y, y2x * w2.y + y2y * w2.x);
        xs[SW(i0 + 3 * q)] = make_float2(y3x * w3.x - y3y * w3.y, y3x * w3.y + y3y * w3.x);
        __syncthreads();
    }
}

// unpack 2 real spectra from packed FFT; clamp to EPS; write to LDS mag rows
__device__ __forceinline__ void unpack_mags(const float2* xs,
    float* __restrict__ magA, float* __restrict__ magB, int tid)
{
    for (int k = tid; k < NFREQ; k += 256) {
        const unsigned rk = __brev((unsigned)k) >> 22;
        const unsigned pk = ((rk & 0x155u) << 1) | ((rk & 0x2AAu) >> 1);
        const unsigned mI = (unsigned)(1024 - k) & 1023u;
        const unsigned rm = __brev(mI) >> 22;
        const unsigned pm = ((rm & 0x155u) << 1) | ((rm & 0x2AAu) >> 1);
        const float2 Zk = xs[SW(pk)];
        const float2 Zm = xs[SW(pm)];
        const float ar = Zk.x + Zm.x, ai = Zk.y - Zm.y;   // 2*A[k]
        const float br = Zk.y + Zm.y, bi = Zk.x - Zm.x;   // 2*B[k]
        magA[k] = fmaxf(0.5f * sqrtf(ar * ar + ai * ai), EPSV);
        magB[k] = fmaxf(0.5f * sqrtf(br * br + bi * bi), EPSV);
    }
    __syncthreads();
}

// ---------------------------------------------------------------------------
// Fused STFT + patch-stats kernel. Block = (time-patch ti, batch b).
// Per frame-pair: FFT(s+i*t)@tA, FFT(s+i*t)@tB, FFT(g_A+i*g_B); then
// accumulate per-freq-patch sums of |s-g|, |t-g|, (s-t)^2 into LDS.
// Writes kgs/pl directly (mag array never exists).
// ---------------------------------------------------------------------------
__global__ __launch_bounds__(256) void stft_patch_kernel(
    const float* __restrict__ s_in, const float* __restrict__ t_in,
    const float* __restrict__ g_in,
    float* __restrict__ kgs, float* __restrict__ pl)
{
    __shared__ float2 xs[1024];
    __shared__ float2 tw[256];
    __shared__ float magS[2][516];
    __shared__ float magT[2][516];
    __shared__ float magG[2][516];
    __shared__ float accAS[NPF], accAT[NPF], accSQ[NPF];

    const int tid = threadIdx.x;
    const int ti  = blockIdx.x;   // 0..64
    const int b   = blockIdx.y;   // 0..15

    const float* sp = s_in + (size_t)b * LEN;
    const float* tp = t_in + (size_t)b * LEN;
    const float* gp = g_in + (size_t)b * LEN;

    {   // tw[j] = exp(-2*pi*i*j/1024), j<256
        float sv, cv;
        sincosf(-6.283185307179586476925f * (float)tid * (1.0f / 1024.0f), &sv, &cv);
        tw[SW(tid)] = make_float2(cv, sv);
    }
    if (tid < NPF) { accAS[tid] = 0.0f; accAT[tid] = 0.0f; accSQ[tid] = 0.0f; }
    __syncthreads();

    for (int u = 0; u < 8; ++u) {
        const int tA = ti * 16 + 2 * u;
        if (tA >= NFRM) break;                 // uniform across block
        const int startA = tA * HOP - PADW;
        const int startB = startA + HOP;

        load_pack(xs, sp, tp, startA, startA, tid);
        fft1024(xs, tw, tid);
        unpack_mags(xs, magS[0], magT[0], tid);

        load_pack(xs, sp, tp, startB, startB, tid);
        fft1024(xs, tw, tid);
        unpack_mags(xs, magS[1], magT[1], tid);

        load_pack(xs, gp, gp, startA, startB, tid);
        fft1024(xs, tw, tid);
        unpack_mags(xs, magG[0], magG[1], tid);

        // stats: sums over 16-freq groups, accumulated across frames.
        #pragma unroll
        for (int par = 0; par < 2; ++par) {
            if (tA + par >= NFRM) break;       // uniform
            #pragma unroll
            for (int it = 0; it < 3; ++it) {
                const int f = tid + 256 * it;
                float sm = 0.0f, tm = 0.0f, gm = 0.0f;
                if (f < NFREQ) { sm = magS[par][f]; tm = magT[par][f]; gm = magG[par][f]; }
                float as = fabsf(sm - gm);
                float at = fabsf(tm - gm);
                float sq = (sm - tm) * (sm - tm);
                #pragma unroll
                for (int off = 8; off >= 1; off >>= 1) {
                    as += __shfl_down(as, off);
                    at += __shfl_down(at, off);
                    sq += __shfl_down(sq, off);
                }
                // leader of each 16-lane group owns a unique acc slot -> plain +=
                if ((tid & 15) == 0 && f < NFREQ) {
                    const int g16 = f >> 4;
                    accAS[g16] += as; accAT[g16] += at; accSQ[g16] += sq;
                }
            }
        }
        // stats reads complete before next unpack writes mags: >=7 barriers between.
    }
    __syncthreads();

    if (tid < NPF) {
        const int p = tid * NPT + ti;          // fi-major patch index
        kgs[b * NPATCH + p] = (accAS[tid] - accAT[tid]) * (1.0f / 256.0f);
        pl [b * NPATCH + p] = accSQ[tid] * (1.0f / 256.0f);
    }
}

// ---------------------------------------------------------------------------
// Top-k per row: 8-bit MSB radix select, wave-level suffix scan (4 barriers/pass).
// Selection set = { u > T } plus lowest-index ties at u == T (jax tie-break).
// ---------------------------------------------------------------------------
__global__ __launch_bounds__(256) void topk_kernel(
    const float* __restrict__ kgs,
    const float* __restrict__ pl,
    float* __restrict__ rowstats)  // [16][3]
{
    __shared__ unsigned ukey[NPATCH];
    __shared__ float    plv[NPATCH];
    __shared__ unsigned hist[256];
    __shared__ unsigned wtot[4];
    __shared__ int      tIdx[NPATCH];
    __shared__ int      tcnt;
    __shared__ unsigned selB, selHi;
    __shared__ float    red[3][4];

    const int tid = threadIdx.x;
    const int b   = blockIdx.x;
    const float* row   = kgs + b * NPATCH;
    const float* plrow = pl  + b * NPATCH;

    float lsum = 0.0f, lpos = 0.0f;
    for (int i = tid; i < NPATCH; i += 256) {
        float v = row[i];
        lsum += v;
        lpos += (v > 0.0f) ? 1.0f : 0.0f;
        plv[i] = plrow[i];
        unsigned u = __float_as_uint(v);
        ukey[i] = (u & 0x80000000u) ? ~u : (u | 0x80000000u);
    }
    if (tid == 0) tcnt = 0;
    __syncthreads();

    unsigned prefix = 0;
    int rem = TOPK;
    #pragma unroll
    for (int pass = 0; pass < 4; ++pass) {
        const int shift = 24 - 8 * pass;
        const unsigned himask = (pass == 0) ? 0u : (0xFFFFFFFFu << (shift + 8));

        hist[tid] = 0;
        __syncthreads();
        for (int i = tid; i < NPATCH; i += 256) {
            unsigned u = ukey[i];
            if ((u & himask) == (prefix & himask))
                atomicAdd(&hist[(u >> shift) & 255u], 1u);
        }
        __syncthreads();

        const unsigned h = hist[tid];
        unsigned v = h;
        const int lane = tid & 63;
        const int w    = tid >> 6;
        #pragma unroll
        for (int off = 1; off < 64; off <<= 1) {
            unsigned tval = __shfl_down(v, off);
            if (lane + off < 64) v += tval;
        }
        if (lane == 0) wtot[w] = v;
        __syncthreads();
        unsigned addv = 0;
        for (int w2 = w + 1; w2 < 4; ++w2) addv += wtot[w2];
        v += addv;                    // suffix sum over bins >= tid
        const unsigned hi = v - h;    // suffix sum over bins >  tid
        if (v >= (unsigned)rem && hi < (unsigned)rem) { selB = (unsigned)tid; selHi = hi; }
        __syncthreads();
        prefix |= (selB << shift);
        rem -= (int)selHi;
        __syncthreads();              // protect selB/hist before next pass
    }

    const unsigned T = prefix;
    float ssum = 0.0f;
    for (int i = tid; i < NPATCH; i += 256) {
        unsigned u = ukey[i];
        if (u > T) {
            ssum += plv[i];
        } else if (u == T) {
            int j = atomicAdd(&tcnt, 1);
            tIdx[j] = i;
        }
    }
    __syncthreads();
    const int m = tcnt;
    if (m == rem) {
        for (int j = tid; j < m; j += 256) ssum += plv[tIdx[j]];
    } else {
        for (int j = tid; j < m; j += 256) {
            const int i = tIdx[j];
            int rank = 0;
            for (int q = 0; q < m; ++q) rank += (tIdx[q] < i) ? 1 : 0;
            if (rank < rem) ssum += plv[i];
        }
    }

    #pragma unroll
    for (int off = 32; off > 0; off >>= 1) {
        ssum += __shfl_down(ssum, off);
        lsum += __shfl_down(lsum, off);
        lpos += __shfl_down(lpos, off);
    }
    if ((tid & 63) == 0) {
        const int wv = tid >> 6;
        red[0][wv] = ssum; red[1][wv] = lsum; red[2][wv] = lpos;
    }
    __syncthreads();
    if (tid == 0) {
        rowstats[b * 3 + 0] = red[0][0] + red[0][1] + red[0][2] + red[0][3];
        rowstats[b * 3 + 1] = red[1][0] + red[1][1] + red[1][2] + red[1][3];
        rowstats[b * 3 + 2] = red[2][0] + red[2][1] + red[2][2] + red[2][3];
    }
}

// ---------------------------------------------------------------------------
// Final reduction over 16 rows -> 4 scalars.
// ---------------------------------------------------------------------------
__global__ __launch_bounds__(64) void final_kernel(
    const float* __restrict__ rowstats,
    float* __restrict__ out)
{
    const int tid = threadIdx.x;
    float loss = 0.0f, ks = 0.0f, pc = 0.0f;
    if (tid < BATCH) {
        loss = rowstats[tid * 3 + 0] * (1.0f / (float)TOPK);
        ks   = rowstats[tid * 3 + 1];
        pc   = rowstats[tid * 3 + 2];
    }
    #pragma unroll
    for (int off = 32; off > 0; off >>= 1) {
        loss += __shfl_down(loss, off);
        ks   += __shfl_down(ks, off);
        pc   += __shfl_down(pc, off);
    }
    if (tid == 0) {
        out[0] = loss * (1.0f / (float)BATCH);
        out[1] = (float)TOPK / (float)NPATCH;
        out[2] = ks * (1.0f / ((float)BATCH * (float)NPATCH));
        out[3] = pc * (1.0f / ((float)BATCH * (float)NPATCH));
    }
}

// ---------------------------------------------------------------------------
extern "C" void kernel_launch(void* const* d_in, const int* in_sizes, int n_in,
                              void* d_out, int out_size, void* d_ws, size_t ws_size,
                              hipStream_t stream)
{
    const float* s_in = (const float*)d_in[0];
    const float* t_in = (const float*)d_in[1];
    const float* g_in = (const float*)d_in[2];
    float* out = (float*)d_out;

    float* kgs = (float*)d_ws;
    float* pl  = kgs + (size_t)BATCH * NPATCH;
    float* rowstats = pl + (size_t)BATCH * NPATCH;

    dim3 g1(NPT, BATCH);
    stft_patch_kernel<<<g1, 256, 0, stream>>>(s_in, t_in, g_in, kgs, pl);

    topk_kernel<<<BATCH, 256, 0, stream>>>(kgs, pl, rowstats);

    final_kernel<<<1, 64, 0, stream>>>(rowstats, out);
}

// Round 5
// 191.419 us; speedup vs baseline: 1.1882x; 1.1882x over previous
//
#include <hip/hip_runtime.h>
#include <hip/hip_bf16.h>
#include <math.h>

// Problem constants (fixed by setup_inputs)
#define BATCH 16
#define LEN   262144
#define HOP   256
#define PADW  512          // n_fft/2
#define NFREQ 513          // rfft bins
#define NFRM  1025         // frames
#define NPAIR 513          // frame pairs (2 frames per FFT)
#define NPT   65           // time patches
#define NPF   33           // freq patches
#define NPATCH 2145        // 33*65
#define TOPK  643          // int(2145*0.3)
#define EPSV  1e-8f
#define PSTRIDE 99         // 33 freq groups * 3 stats

// LDS bank-conflict swizzle: float2 element i lives at phys i^((i>>4)&15).
#define SW(i) ((i) ^ (((i) >> 4) & 15))

__device__ __forceinline__ int reflect_idx(int g) {
    g = (g < 0) ? -g : g;
    g = (g >= LEN) ? (2 * LEN - 2 - g) : g;
    return g;
}

// load packed frame: xs[i] = re_src[refl(startRe+i)] + i*im_src[refl(startIm+i)]
__device__ __forceinline__ void load_pack(float2* xs,
    const float* __restrict__ re_src, const float* __restrict__ im_src,
    int startRe, int startIm, int tid)
{
    #pragma unroll
    for (int m = 0; m < 4; ++m) {
        const int i = tid + 256 * m;
        xs[SW(i)] = make_float2(re_src[reflect_idx(startRe + i)],
                                im_src[reflect_idx(startIm + i)]);
    }
    __syncthreads();
}

// 1024-pt radix-4 DIF complex FFT. Natural input, base-4 digit-reversed output.
// Only w1 read from table (exponent < 256 always); w2=w1^2, w3=w2*w1.
__device__ __forceinline__ void fft1024(float2* xs, const float2* tw, int tid) {
    #pragma unroll
    for (int s = 0; s < 5; ++s) {
        const int lenlog = 10 - 2 * s;
        const int q      = 1 << (lenlog - 2);
        const int pos    = tid & (q - 1);
        const int blk    = tid >> (lenlog - 2);
        const int i0     = (blk << lenlog) + pos;

        float2 a  = xs[SW(i0)];
        float2 bb = xs[SW(i0 + q)];
        float2 c  = xs[SW(i0 + 2 * q)];
        float2 d  = xs[SW(i0 + 3 * q)];

        const float t0x = a.x + c.x,  t0y = a.y + c.y;
        const float t1x = a.x - c.x,  t1y = a.y - c.y;
        const float t2x = bb.x + d.x, t2y = bb.y + d.y;
        const float t3x = bb.x - d.x, t3y = bb.y - d.y;

        // w4 = -i butterfly
        const float y0x = t0x + t2x, y0y = t0y + t2y;
        const float y1x = t1x + t3y, y1y = t1y - t3x;
        const float y2x = t0x - t2x, y2y = t0y - t2y;
        const float y3x = t1x - t3y, y3y = t1y + t3x;

        const int e = pos << (2 * s);           // always < 256
        const float2 w1 = tw[SW(e)];
        const float2 w2 = make_float2(w1.x * w1.x - w1.y * w1.y, 2.0f * w1.x * w1.y);
        const float2 w3 = make_float2(w2.x * w1.x - w2.y * w1.y, w2.x * w1.y + w2.y * w1.x);

        xs[SW(i0)]         = make_float2(y0x, y0y);
        xs[SW(i0 + q)]     = make_float2(y1x * w1.x - y1y * w1.y, y1x * w1.y + y1y * w1.x);
        xs[SW(i0 + 2 * q)] = make_float2(y2x * w2.x - y2y * w2.y, y2x * w2.y + y2y * w2.x);
        xs[SW(i0 + 3 * q)] = make_float2(y3x * w3.x - y3y * w3.y, y3x * w3.y + y3y * w3.x);
        __syncthreads();
    }
}

// unpack 2 real spectra from packed FFT; clamp to EPS; write to LDS mag rows
__device__ __forceinline__ void unpack_mags(const float2* xs,
    float* __restrict__ magA, float* __restrict__ magB, int tid)
{
    for (int k = tid; k < NFREQ; k += 256) {
        const unsigned rk = __brev((unsigned)k) >> 22;
        const unsigned pk = ((rk & 0x155u) << 1) | ((rk & 0x2AAu) >> 1);
        const unsigned mI = (unsigned)(1024 - k) & 1023u;
        const unsigned rm = __brev(mI) >> 22;
        const unsigned pm = ((rm & 0x155u) << 1) | ((rm & 0x2AAu) >> 1);
        const float2 Zk = xs[SW(pk)];
        const float2 Zm = xs[SW(pm)];
        const float ar = Zk.x + Zm.x, ai = Zk.y - Zm.y;   // 2*A[k]
        const float br = Zk.y + Zm.y, bi = Zk.x - Zm.x;   // 2*B[k]
        magA[k] = fmaxf(0.5f * sqrtf(ar * ar + ai * ai), EPSV);
        magB[k] = fmaxf(0.5f * sqrtf(br * br + bi * bi), EPSV);
    }
    __syncthreads();
}

// ---------------------------------------------------------------------------
// Fused STFT + patch-partials. Block = (frame-pair p, batch b); 8208 blocks.
// 3 FFTs: (s+i*t)@fA, (s+i*t)@fB, (g@fA + i*g@fB). Then 16-lane shuffle
// reductions produce 33 freq-group partials x 3 stats for this pair, written
// to part[b][p][99]. The 101 MB mag array never exists.
// ---------------------------------------------------------------------------
__global__ __launch_bounds__(256) void stft_pair_kernel(
    const float* __restrict__ s_in, const float* __restrict__ t_in,
    const float* __restrict__ g_in,
    float* __restrict__ part)
{
    __shared__ float2 xs[1024];
    __shared__ float2 tw[256];
    __shared__ float magS[2][516];
    __shared__ float magT[2][516];
    __shared__ float magG[2][516];

    const int tid = threadIdx.x;
    const int p   = blockIdx.x;   // 0..512
    const int b   = blockIdx.y;   // 0..15

    const float* sp = s_in + (size_t)b * LEN;
    const float* tp = t_in + (size_t)b * LEN;
    const float* gp = g_in + (size_t)b * LEN;

    {   // tw[j] = exp(-2*pi*i*j/1024), j<256
        float sv, cv;
        sincosf(-6.283185307179586476925f * (float)tid * (1.0f / 1024.0f), &sv, &cv);
        tw[SW(tid)] = make_float2(cv, sv);
    }

    const bool hasB  = (2 * p + 1) < NFRM;     // pair 512 has only frame 1024
    const int startA = 2 * p * HOP - PADW;
    const int startB = startA + HOP;

    load_pack(xs, sp, tp, startA, startA, tid);
    fft1024(xs, tw, tid);
    unpack_mags(xs, magS[0], magT[0], tid);

    if (hasB) {
        load_pack(xs, sp, tp, startB, startB, tid);
        fft1024(xs, tw, tid);
        unpack_mags(xs, magS[1], magT[1], tid);
    }

    load_pack(xs, gp, gp, startA, startB, tid);
    fft1024(xs, tw, tid);
    unpack_mags(xs, magG[0], magG[1], tid);

    // per-freq-group stats for this pair; leaders accumulate both frames in regs
    float* prow = part + ((size_t)b * NPAIR + p) * PSTRIDE;
    #pragma unroll
    for (int it = 0; it < 3; ++it) {
        const int f = tid + 256 * it;
        float asum = 0.0f, atsum = 0.0f, sqsum = 0.0f;
        #pragma unroll
        for (int par = 0; par < 2; ++par) {
            if (par == 1 && !hasB) break;      // uniform
            float sm = 0.0f, tm = 0.0f, gm = 0.0f;
            if (f < NFREQ) { sm = magS[par][f]; tm = magT[par][f]; gm = magG[par][f]; }
            float as = fabsf(sm - gm);
            float at = fabsf(tm - gm);
            float sq = (sm - tm) * (sm - tm);
            #pragma unroll
            for (int off = 8; off >= 1; off >>= 1) {
                as += __shfl_down(as, off);
                at += __shfl_down(at, off);
                sq += __shfl_down(sq, off);
            }
            asum += as; atsum += at; sqsum += sq;
        }
        if ((tid & 15) == 0 && f < NFREQ) {
            const int g16 = f >> 4;            // unique per (leader, it)
            prow[g16 * 3 + 0] = asum;
            prow[g16 * 3 + 1] = atsum;
            prow[g16 * 3 + 2] = sqsum;
        }
    }
}

// ---------------------------------------------------------------------------
// Combine pair-partials -> kgs, pl. Block = (time-patch ti, batch b).
// Deterministic fixed-order sum over the 8 pairs of the time patch.
// ---------------------------------------------------------------------------
__global__ __launch_bounds__(128) void combine_kernel(
    const float* __restrict__ part,
    float* __restrict__ kgs, float* __restrict__ pl)
{
    __shared__ float sh[PSTRIDE];
    const int tid = threadIdx.x;
    const int ti  = blockIdx.x;   // 0..64
    const int b   = blockIdx.y;

    if (tid < PSTRIDE) {
        float acc = 0.0f;
        const int p0 = ti * 8;
        #pragma unroll
        for (int u = 0; u < 8; ++u) {
            const int p = p0 + u;
            if (p < NPAIR) acc += part[((size_t)b * NPAIR + p) * PSTRIDE + tid];
        }
        sh[tid] = acc;
    }
    __syncthreads();
    if (tid < NPF) {
        const int pt = tid * NPT + ti;         // fi-major patch index
        kgs[b * NPATCH + pt] = (sh[3 * tid] - sh[3 * tid + 1]) * (1.0f / 256.0f);
        pl [b * NPATCH + pt] = sh[3 * tid + 2] * (1.0f / 256.0f);
    }
}

// ---------------------------------------------------------------------------
// Top-k per row: 8-bit MSB radix select, wave-level suffix scan.
// Selection set = { u > T } plus lowest-index ties at u == T (jax tie-break).
// ---------------------------------------------------------------------------
__global__ __launch_bounds__(256) void topk_kernel(
    const float* __restrict__ kgs,
    const float* __restrict__ pl,
    float* __restrict__ rowstats)  // [16][3]
{
    __shared__ unsigned ukey[NPATCH];
    __shared__ float    plv[NPATCH];
    __shared__ unsigned hist[256];
    __shared__ unsigned wtot[4];
    __shared__ int      tIdx[NPATCH];
    __shared__ int      tcnt;
    __shared__ unsigned selB, selHi;
    __shared__ float    red[3][4];

    const int tid = threadIdx.x;
    const int b   = blockIdx.x;
    const float* row   = kgs + b * NPATCH;
    const float* plrow = pl  + b * NPATCH;

    float lsum = 0.0f, lpos = 0.0f;
    for (int i = tid; i < NPATCH; i += 256) {
        float v = row[i];
        lsum += v;
        lpos += (v > 0.0f) ? 1.0f : 0.0f;
        plv[i] = plrow[i];
        unsigned u = __float_as_uint(v);
        ukey[i] = (u & 0x80000000u) ? ~u : (u | 0x80000000u);
    }
    if (tid == 0) tcnt = 0;
    __syncthreads();

    unsigned prefix = 0;
    int rem = TOPK;
    #pragma unroll
    for (int pass = 0; pass < 4; ++pass) {
        const int shift = 24 - 8 * pass;
        const unsigned himask = (pass == 0) ? 0u : (0xFFFFFFFFu << (shift + 8));

        hist[tid] = 0;
        __syncthreads();
        for (int i = tid; i < NPATCH; i += 256) {
            unsigned u = ukey[i];
            if ((u & himask) == (prefix & himask))
                atomicAdd(&hist[(u >> shift) & 255u], 1u);
        }
        __syncthreads();

        const unsigned h = hist[tid];
        unsigned v = h;
        const int lane = tid & 63;
        const int w    = tid >> 6;
        #pragma unroll
        for (int off = 1; off < 64; off <<= 1) {
            unsigned tval = __shfl_down(v, off);
            if (lane + off < 64) v += tval;
        }
        if (lane == 0) wtot[w] = v;
        __syncthreads();
        unsigned addv = 0;
        for (int w2 = w + 1; w2 < 4; ++w2) addv += wtot[w2];
        v += addv;                    // suffix sum over bins >= tid
        const unsigned hi = v - h;    // suffix sum over bins >  tid
        if (v >= (unsigned)rem && hi < (unsigned)rem) { selB = (unsigned)tid; selHi = hi; }
        __syncthreads();
        prefix |= (selB << shift);
        rem -= (int)selHi;
        __syncthreads();              // protect selB/hist before next pass
    }

    const unsigned T = prefix;
    float ssum = 0.0f;
    for (int i = tid; i < NPATCH; i += 256) {
        unsigned u = ukey[i];
        if (u > T) {
            ssum += plv[i];
        } else if (u == T) {
            int j = atomicAdd(&tcnt, 1);
            tIdx[j] = i;
        }
    }
    __syncthreads();
    const int m = tcnt;
    if (m == rem) {
        for (int j = tid; j < m; j += 256) ssum += plv[tIdx[j]];
    } else {
        for (int j = tid; j < m; j += 256) {
            const int i = tIdx[j];
            int rank = 0;
            for (int q = 0; q < m; ++q) rank += (tIdx[q] < i) ? 1 : 0;
            if (rank < rem) ssum += plv[i];
        }
    }

    #pragma unroll
    for (int off = 32; off > 0; off >>= 1) {
        ssum += __shfl_down(ssum, off);
        lsum += __shfl_down(lsum, off);
        lpos += __shfl_down(lpos, off);
    }
    if ((tid & 63) == 0) {
        const int wv = tid >> 6;
        red[0][wv] = ssum; red[1][wv] = lsum; red[2][wv] = lpos;
    }
    __syncthreads();
    if (tid == 0) {
        rowstats[b * 3 + 0] = red[0][0] + red[0][1] + red[0][2] + red[0][3];
        rowstats[b * 3 + 1] = red[1][0] + red[1][1] + red[1][2] + red[1][3];
        rowstats[b * 3 + 2] = red[2][0] + red[2][1] + red[2][2] + red[2][3];
    }
}

// ---------------------------------------------------------------------------
// Final reduction over 16 rows -> 4 scalars.
// ---------------------------------------------------------------------------
__global__ __launch_bounds__(64) void final_kernel(
    const float* __restrict__ rowstats,
    float* __restrict__ out)
{
    const int tid = threadIdx.x;
    float loss = 0.0f, ks = 0.0f, pc = 0.0f;
    if (tid < BATCH) {
        loss = rowstats[tid * 3 + 0] * (1.0f / (float)TOPK);
        ks   = rowstats[tid * 3 + 1];
        pc   = rowstats[tid * 3 + 2];
    }
    #pragma unroll
    for (int off = 32; off > 0; off >>= 1) {
        loss += __shfl_down(loss, off);
        ks   += __shfl_down(ks, off);
        pc   += __shfl_down(pc, off);
    }
    if (tid == 0) {
        out[0] = loss * (1.0f / (float)BATCH);
        out[1] = (float)TOPK / (float)NPATCH;
        out[2] = ks * (1.0f / ((float)BATCH * (float)NPATCH));
        out[3] = pc * (1.0f / ((float)BATCH * (float)NPATCH));
    }
}

// ---------------------------------------------------------------------------
extern "C" void kernel_launch(void* const* d_in, const int* in_sizes, int n_in,
                              void* d_out, int out_size, void* d_ws, size_t ws_size,
                              hipStream_t stream)
{
    const float* s_in = (const float*)d_in[0];
    const float* t_in = (const float*)d_in[1];
    const float* g_in = (const float*)d_in[2];
    float* out = (float*)d_out;

    float* part = (float*)d_ws;                               // 16*513*99 floats
    float* kgs  = part + (size_t)BATCH * NPAIR * PSTRIDE;
    float* pl   = kgs + (size_t)BATCH * NPATCH;
    float* rowstats = pl + (size_t)BATCH * NPATCH;

    dim3 g1(NPAIR, BATCH);
    stft_pair_kernel<<<g1, 256, 0, stream>>>(s_in, t_in, g_in, part);

    dim3 g2(NPT, BATCH);
    combine_kernel<<<g2, 128, 0, stream>>>(part, kgs, pl);

    topk_kernel<<<BATCH, 256, 0, stream>>>(kgs, pl, rowstats);

    final_kernel<<<1, 64, 0, stream>>>(rowstats, out);
}

// Round 6
// 186.659 us; speedup vs baseline: 1.2185x; 1.0255x over previous
//
#include <hip/hip_runtime.h>
#include <hip/hip_bf16.h>
#include <math.h>

// Problem constants (fixed by setup_inputs)
#define BATCH 16
#define LEN   262144
#define HOP   256
#define PADW  512          // n_fft/2
#define NFREQ 513          // rfft bins
#define NFRM  1025         // frames
#define NPAIR 513          // frame pairs (2 frames per FFT)
#define NPT   65           // time patches
#define NPF   33           // freq patches
#define NPATCH 2145        // 33*65
#define TOPK  643          // int(2145*0.3)
#define EPSV  1e-8f

// LDS bank-conflict swizzle: float2 element i lives at phys i^((i>>4)&15).
#define SW(i) ((i) ^ (((i) >> 4) & 15))

__device__ __forceinline__ int reflect_idx(int g) {
    g = (g < 0) ? -g : g;
    g = (g >= LEN) ? (2 * LEN - 2 - g) : g;
    return g;
}

// load packed frame: xs[i] = re_src[refl(startRe+i)] + i*im_src[refl(startIm+i)]
__device__ __forceinline__ void load_pack(float2* xs,
    const float* __restrict__ re_src, const float* __restrict__ im_src,
    int startRe, int startIm, int tid)
{
    #pragma unroll
    for (int m = 0; m < 4; ++m) {
        const int i = tid + 256 * m;
        xs[SW(i)] = make_float2(re_src[reflect_idx(startRe + i)],
                                im_src[reflect_idx(startIm + i)]);
    }
    __syncthreads();
}

// 1024-pt radix-4 DIF complex FFT. Natural input, base-4 digit-reversed output.
// Only w1 read from table (exponent < 256 always); w2=w1^2, w3=w2*w1.
__device__ __forceinline__ void fft1024(float2* xs, const float2* tw, int tid) {
    #pragma unroll
    for (int s = 0; s < 5; ++s) {
        const int lenlog = 10 - 2 * s;
        const int q      = 1 << (lenlog - 2);
        const int pos    = tid & (q - 1);
        const int blk    = tid >> (lenlog - 2);
        const int i0     = (blk << lenlog) + pos;

        float2 a  = xs[SW(i0)];
        float2 bb = xs[SW(i0 + q)];
        float2 c  = xs[SW(i0 + 2 * q)];
        float2 d  = xs[SW(i0 + 3 * q)];

        const float t0x = a.x + c.x,  t0y = a.y + c.y;
        const float t1x = a.x - c.x,  t1y = a.y - c.y;
        const float t2x = bb.x + d.x, t2y = bb.y + d.y;
        const float t3x = bb.x - d.x, t3y = bb.y - d.y;

        // w4 = -i butterfly
        const float y0x = t0x + t2x, y0y = t0y + t2y;
        const float y1x = t1x + t3y, y1y = t1y - t3x;
        const float y2x = t0x - t2x, y2y = t0y - t2y;
        const float y3x = t1x - t3y, y3y = t1y + t3x;

        const int e = pos << (2 * s);           // always < 256
        const float2 w1 = tw[SW(e)];
        const float2 w2 = make_float2(w1.x * w1.x - w1.y * w1.y, 2.0f * w1.x * w1.y);
        const float2 w3 = make_float2(w2.x * w1.x - w2.y * w1.y, w2.x * w1.y + w2.y * w1.x);

        xs[SW(i0)]         = make_float2(y0x, y0y);
        xs[SW(i0 + q)]     = make_float2(y1x * w1.x - y1y * w1.y, y1x * w1.y + y1y * w1.x);
        xs[SW(i0 + 2 * q)] = make_float2(y2x * w2.x - y2y * w2.y, y2x * w2.y + y2y * w2.x);
        xs[SW(i0 + 3 * q)] = make_float2(y3x * w3.x - y3y * w3.y, y3x * w3.y + y3y * w3.x);
        __syncthreads();
    }
}

// unpack both real spectra at bin k from packed FFT result (in LDS), reg out.
__device__ __forceinline__ void unpack_k(const float2* xs, int k,
                                         float& mx, float& my)
{
    const unsigned rk = __brev((unsigned)k) >> 22;
    const unsigned pk = ((rk & 0x155u) << 1) | ((rk & 0x2AAu) >> 1);
    const unsigned mI = (unsigned)(1024 - k) & 1023u;
    const unsigned rm = __brev(mI) >> 22;
    const unsigned pm = ((rm & 0x155u) << 1) | ((rm & 0x2AAu) >> 1);
    const float2 Zk = xs[SW(pk)];
    const float2 Zm = xs[SW(pm)];
    const float ar = Zk.x + Zm.x, ai = Zk.y - Zm.y;   // 2*X[k]
    const float br = Zk.y + Zm.y, bi = Zk.x - Zm.x;   // 2*Y[k]
    mx = fmaxf(0.5f * sqrtf(ar * ar + ai * ai), EPSV);
    my = fmaxf(0.5f * sqrtf(br * br + bi * bi), EPSV);
}

// ---------------------------------------------------------------------------
// Fused STFT + patch-partials, register-staged. Block = (pair p, batch b).
// Thread tid owns bins {tid, tid+256, tid+512} of every FFT, so s,t,g mags
// meet in registers; no LDS mag staging. part layout [b][g16][pair][3] so a
// patch's 8 pair-partials are 24 contiguous floats for the topk kernel.
// ---------------------------------------------------------------------------
__global__ __launch_bounds__(256) void stft_pair_kernel(
    const float* __restrict__ s_in, const float* __restrict__ t_in,
    const float* __restrict__ g_in,
    float* __restrict__ part)
{
    __shared__ float2 xs[1024];
    __shared__ float2 tw[256];

    const int tid = threadIdx.x;
    const int p   = blockIdx.x;   // 0..512
    const int b   = blockIdx.y;   // 0..15

    const float* sp = s_in + (size_t)b * LEN;
    const float* tp = t_in + (size_t)b * LEN;
    const float* gp = g_in + (size_t)b * LEN;

    {   // tw[j] = exp(-2*pi*i*j/1024), j<256
        float sv, cv;
        sincosf(-6.283185307179586476925f * (float)tid * (1.0f / 1024.0f), &sv, &cv);
        tw[SW(tid)] = make_float2(cv, sv);
    }

    const bool hasB  = (2 * p + 1) < NFRM;     // pair 512 has only frame 1024
    const int startA = 2 * p * HOP - PADW;
    const int startB = startA + HOP;

    float sA[3] = {0, 0, 0}, tA[3] = {0, 0, 0};
    float sB[3] = {0, 0, 0}, tB[3] = {0, 0, 0};

    // FFT1: s + i*t at frame A
    load_pack(xs, sp, tp, startA, startA, tid);
    fft1024(xs, tw, tid);
    #pragma unroll
    for (int it = 0; it < 3; ++it) {
        const int k = tid + 256 * it;
        if (k <= 512) unpack_k(xs, k, sA[it], tA[it]);
    }
    __syncthreads();   // xs reads done before next load overwrites

    // FFT2: s + i*t at frame B
    if (hasB) {
        load_pack(xs, sp, tp, startB, startB, tid);
        fft1024(xs, tw, tid);
        #pragma unroll
        for (int it = 0; it < 3; ++it) {
            const int k = tid + 256 * it;
            if (k <= 512) unpack_k(xs, k, sB[it], tB[it]);
        }
        __syncthreads();
    }

    // FFT3: g@A + i*g@B
    load_pack(xs, gp, gp, startA, startB, tid);
    fft1024(xs, tw, tid);

    // stats per bin; reduce A and B separately (preserves prior fp order)
    #pragma unroll
    for (int it = 0; it < 3; ++it) {
        const int k = tid + 256 * it;
        const bool valid = (k <= 512);
        float gA_ = 0.0f, gB_ = 0.0f;
        if (valid) unpack_k(xs, k, gA_, gB_);

        float asum = 0.0f, atsum = 0.0f, sqsum = 0.0f;
        {   // frame A
            float as = 0.0f, at = 0.0f, sq = 0.0f;
            if (valid) {
                as = fabsf(sA[it] - gA_);
                at = fabsf(tA[it] - gA_);
                sq = (sA[it] - tA[it]) * (sA[it] - tA[it]);
            }
            #pragma unroll
            for (int off = 8; off >= 1; off >>= 1) {
                as += __shfl_down(as, off);
                at += __shfl_down(at, off);
                sq += __shfl_down(sq, off);
            }
            asum += as; atsum += at; sqsum += sq;
        }
        if (hasB) {  // frame B
            float as = 0.0f, at = 0.0f, sq = 0.0f;
            if (valid) {
                as = fabsf(sB[it] - gB_);
                at = fabsf(tB[it] - gB_);
                sq = (sB[it] - tB[it]) * (sB[it] - tB[it]);
            }
            #pragma unroll
            for (int off = 8; off >= 1; off >>= 1) {
                as += __shfl_down(as, off);
                at += __shfl_down(at, off);
                sq += __shfl_down(sq, off);
            }
            asum += as; atsum += at; sqsum += sq;
        }
        if ((tid & 15) == 0 && valid) {
            const int g16 = k >> 4;            // 0..32, unique per (leader, it)
            float* slot = part + (((size_t)b * NPF + g16) * NPAIR + p) * 3;
            slot[0] = asum; slot[1] = atsum; slot[2] = sqsum;
        }
    }
}

// ---------------------------------------------------------------------------
// Fused combine + top-k per batch row. 1024 threads, 1 block per row.
// Phase A: patch sums from part (24 contiguous floats per patch).
// Phase B: 8-bit MSB radix select (threshold T = TOPK-th largest key).
// Phase C: selected patch_loss sum; jax tie-break (lowest index at T).
// ---------------------------------------------------------------------------
__global__ __launch_bounds__(1024) void topk_kernel(
    const float* __restrict__ part,
    float* __restrict__ rowstats)  // [16][3] = {selected_sum, kgs_sum, pos_count}
{
    __shared__ unsigned ukey[NPATCH];
    __shared__ float    plv[NPATCH];
    __shared__ unsigned hist[256];
    __shared__ unsigned wtot[4];
    __shared__ int      tIdx[NPATCH];
    __shared__ int      tcnt;
    __shared__ unsigned selB, selHi;
    __shared__ float    red[3][16];

    const int tid = threadIdx.x;
    const int b   = blockIdx.x;

    // Phase A: combine pair partials -> kgs key + patch_loss, in LDS.
    float lsum = 0.0f, lpos = 0.0f;
    for (int p2 = tid; p2 < NPATCH; p2 += 1024) {
        const int fi = p2 / NPT;
        const int ti = p2 - fi * NPT;
        const float* base = part + (((size_t)b * NPF + fi) * NPAIR + ti * 8) * 3;
        float a = 0.0f, t3 = 0.0f, q = 0.0f;
        #pragma unroll
        for (int u = 0; u < 8; ++u) {
            if (ti * 8 + u < NPAIR) {
                a  += base[u * 3 + 0];
                t3 += base[u * 3 + 1];
                q  += base[u * 3 + 2];
            }
        }
        const float kg = (a - t3) * (1.0f / 256.0f);
        lsum += kg;
        lpos += (kg > 0.0f) ? 1.0f : 0.0f;
        plv[p2] = q * (1.0f / 256.0f);
        unsigned u32 = __float_as_uint(kg);
        ukey[p2] = (u32 & 0x80000000u) ? ~u32 : (u32 | 0x80000000u);
    }
    if (tid == 0) tcnt = 0;
    __syncthreads();

    // Phase B: radix select.
    unsigned prefix = 0;
    int rem = TOPK;
    #pragma unroll
    for (int pass = 0; pass < 4; ++pass) {
        const int shift = 24 - 8 * pass;
        const unsigned himask = (pass == 0) ? 0u : (0xFFFFFFFFu << (shift + 8));

        if (tid < 256) hist[tid] = 0;
        __syncthreads();
        for (int i = tid; i < NPATCH; i += 1024) {
            unsigned u = ukey[i];
            if ((u & himask) == (prefix & himask))
                atomicAdd(&hist[(u >> shift) & 255u], 1u);
        }
        __syncthreads();

        if (tid < 256) {
            const unsigned h = hist[tid];
            unsigned v = h;
            const int lane = tid & 63;
            const int w    = tid >> 6;
            #pragma unroll
            for (int off = 1; off < 64; off <<= 1) {
                unsigned tval = __shfl_down(v, off);
                if (lane + off < 64) v += tval;
            }
            if (lane == 0) wtot[w] = v;
            __syncthreads();
            unsigned addv = 0;
            for (int w2 = w + 1; w2 < 4; ++w2) addv += wtot[w2];
            v += addv;                    // suffix sum over bins >= tid
            const unsigned hi = v - h;    // suffix sum over bins >  tid
            if (v >= (unsigned)rem && hi < (unsigned)rem) { selB = (unsigned)tid; selHi = hi; }
        } else {
            __syncthreads();              // match the barrier inside the guard
        }
        __syncthreads();
        prefix |= (selB << shift);
        rem -= (int)selHi;
        __syncthreads();                  // protect selB/hist before next pass
    }

    // Phase C: selected sums.
    const unsigned T = prefix;
    float ssum = 0.0f;
    for (int i = tid; i < NPATCH; i += 1024) {
        unsigned u = ukey[i];
        if (u > T) {
            ssum += plv[i];
        } else if (u == T) {
            int j = atomicAdd(&tcnt, 1);
            tIdx[j] = i;
        }
    }
    __syncthreads();
    const int m = tcnt;
    if (m == rem) {
        for (int j = tid; j < m; j += 1024) ssum += plv[tIdx[j]];
    } else {
        for (int j = tid; j < m; j += 1024) {
            const int i = tIdx[j];
            int rank = 0;
            for (int q = 0; q < m; ++q) rank += (tIdx[q] < i) ? 1 : 0;
            if (rank < rem) ssum += plv[i];
        }
    }

    #pragma unroll
    for (int off = 32; off > 0; off >>= 1) {
        ssum += __shfl_down(ssum, off);
        lsum += __shfl_down(lsum, off);
        lpos += __shfl_down(lpos, off);
    }
    if ((tid & 63) == 0) {
        const int wv = tid >> 6;
        red[0][wv] = ssum; red[1][wv] = lsum; red[2][wv] = lpos;
    }
    __syncthreads();
    if (tid == 0) {
        float a = 0.0f, c = 0.0f, d = 0.0f;
        #pragma unroll
        for (int i = 0; i < 16; ++i) { a += red[0][i]; c += red[1][i]; d += red[2][i]; }
        rowstats[b * 3 + 0] = a;
        rowstats[b * 3 + 1] = c;
        rowstats[b * 3 + 2] = d;
    }
}

// ---------------------------------------------------------------------------
// Final reduction over 16 rows -> 4 scalars.
// ---------------------------------------------------------------------------
__global__ __launch_bounds__(64) void final_kernel(
    const float* __restrict__ rowstats,
    float* __restrict__ out)
{
    const int tid = threadIdx.x;
    float loss = 0.0f, ks = 0.0f, pc = 0.0f;
    if (tid < BATCH) {
        loss = rowstats[tid * 3 + 0] * (1.0f / (float)TOPK);
        ks   = rowstats[tid * 3 + 1];
        pc   = rowstats[tid * 3 + 2];
    }
    #pragma unroll
    for (int off = 32; off > 0; off >>= 1) {
        loss += __shfl_down(loss, off);
        ks   += __shfl_down(ks, off);
        pc   += __shfl_down(pc, off);
    }
    if (tid == 0) {
        out[0] = loss * (1.0f / (float)BATCH);
        out[1] = (float)TOPK / (float)NPATCH;
        out[2] = ks * (1.0f / ((float)BATCH * (float)NPATCH));
        out[3] = pc * (1.0f / ((float)BATCH * (float)NPATCH));
    }
}

// ---------------------------------------------------------------------------
extern "C" void kernel_launch(void* const* d_in, const int* in_sizes, int n_in,
                              void* d_out, int out_size, void* d_ws, size_t ws_size,
                              hipStream_t stream)
{
    const float* s_in = (const float*)d_in[0];
    const float* t_in = (const float*)d_in[1];
    const float* g_in = (const float*)d_in[2];
    float* out = (float*)d_out;

    float* part = (float*)d_ws;                               // 16*33*513*3 floats
    float* rowstats = part + (size_t)BATCH * NPF * NPAIR * 3;

    dim3 g1(NPAIR, BATCH);
    stft_pair_kernel<<<g1, 256, 0, stream>>>(s_in, t_in, g_in, part);

    topk_kernel<<<BATCH, 1024, 0, stream>>>(part, rowstats);

    final_kernel<<<1, 64, 0, stream>>>(rowstats, out);
}

// Round 8
// 181.775 us; speedup vs baseline: 1.2513x; 1.0269x over previous
//
#include <hip/hip_runtime.h>
#include <hip/hip_bf16.h>
#include <math.h>

// Problem constants (fixed by setup_inputs)
#define BATCH 16
#define LEN   262144
#define HOP   256
#define PADW  512          // n_fft/2
#define NFREQ 513          // rfft bins
#define NFRM  1025         // frames
#define NPAIR 513          // frame pairs (2 frames per FFT)
#define NPT   65           // time patches
#define NPF   33           // freq patches
#define NPATCH 2145        // 33*65
#define TOPK  643          // int(2145*0.3)
#define EPSV  1e-8f

// LDS bank-conflict swizzle: float2 element i lives at phys i^((i>>4)&15).
// NOTE: for j<4 and i0=4t, SW(i0+j) = SW(i0) ^ j  (XOR, NOT +j: the mask's
// low-2 bits make SW(i0) odd-aligned; adding j would carry. R7 bug.)
#define SW(i) ((i) ^ (((i) >> 4) & 15))

__device__ __forceinline__ int reflect_idx(int g) {
    g = (g < 0) ? -g : g;
    g = (g >= LEN) ? (2 * LEN - 2 - g) : g;
    return g;
}

// scalar (edge) load with reflect padding (jnp 'reflect': no edge repeat)
__device__ __forceinline__ void load_pack_edge(float2* xs,
    const float* __restrict__ re_src, const float* __restrict__ im_src,
    int startRe, int startIm, int tid)
{
    #pragma unroll
    for (int m = 0; m < 4; ++m) {
        const int i = tid + 256 * m;
        xs[SW(i)] = make_float2(re_src[reflect_idx(startRe + i)],
                                im_src[reflect_idx(startIm + i)]);
    }
    __syncthreads();
}

// interior fast path: fully in-bounds, float4 loads (16B aligned: start%256==0)
__device__ __forceinline__ void load_pack_fast(float2* xs,
    const float* __restrict__ re_src, const float* __restrict__ im_src,
    int startRe, int startIm, int tid)
{
    const float4 r4 = *reinterpret_cast<const float4*>(re_src + startRe + 4 * tid);
    const float4 i4 = *reinterpret_cast<const float4*>(im_src + startIm + 4 * tid);
    const int base = SW(4 * tid);
    xs[base ^ 0] = make_float2(r4.x, i4.x);   // SW(4t+j) = SW(4t) ^ j
    xs[base ^ 1] = make_float2(r4.y, i4.y);
    xs[base ^ 2] = make_float2(r4.z, i4.z);
    xs[base ^ 3] = make_float2(r4.w, i4.w);
    __syncthreads();
}

// 1024-pt radix-4 DIF complex FFT. Natural input, base-4 digit-reversed output.
// Stage 0 twiddle comes from registers (w0 = this thread's sincos); stage 4 has
// identity twiddles (elided); stages 1-3 read w1 from table, w2=w1^2, w3=w2*w1.
__device__ __forceinline__ void fft1024(float2* xs, const float2* tw, float2 w0, int tid) {
    #pragma unroll
    for (int s = 0; s < 5; ++s) {
        const int lenlog = 10 - 2 * s;
        const int q      = 1 << (lenlog - 2);
        const int pos    = tid & (q - 1);
        const int blk    = tid >> (lenlog - 2);
        const int i0     = (blk << lenlog) + pos;

        float2 a  = xs[SW(i0)];
        float2 bb = xs[SW(i0 + q)];
        float2 c  = xs[SW(i0 + 2 * q)];
        float2 d  = xs[SW(i0 + 3 * q)];

        const float t0x = a.x + c.x,  t0y = a.y + c.y;
        const float t1x = a.x - c.x,  t1y = a.y - c.y;
        const float t2x = bb.x + d.x, t2y = bb.y + d.y;
        const float t3x = bb.x - d.x, t3y = bb.y - d.y;

        // w4 = -i butterfly
        const float y0x = t0x + t2x, y0y = t0y + t2y;
        const float y1x = t1x + t3y, y1y = t1y - t3x;
        const float y2x = t0x - t2x, y2y = t0y - t2y;
        const float y3x = t1x - t3y, y3y = t1y + t3x;

        if (s == 4) {
            // q=1, pos=0 -> all twiddles are 1; i0 = 4*tid
            const int o = SW(i0);
            xs[o ^ 0] = make_float2(y0x, y0y);   // XOR addressing (see SW note)
            xs[o ^ 1] = make_float2(y1x, y1y);
            xs[o ^ 2] = make_float2(y2x, y2y);
            xs[o ^ 3] = make_float2(y3x, y3y);
        } else {
            const float2 w1 = (s == 0) ? w0 : tw[SW(pos << (2 * s))];
            const float2 w2 = make_float2(w1.x * w1.x - w1.y * w1.y, 2.0f * w1.x * w1.y);
            const float2 w3 = make_float2(w2.x * w1.x - w2.y * w1.y, w2.x * w1.y + w2.y * w1.x);
            xs[SW(i0)]         = make_float2(y0x, y0y);
            xs[SW(i0 + q)]     = make_float2(y1x * w1.x - y1y * w1.y, y1x * w1.y + y1y * w1.x);
            xs[SW(i0 + 2 * q)] = make_float2(y2x * w2.x - y2y * w2.y, y2x * w2.y + y2y * w2.x);
            xs[SW(i0 + 3 * q)] = make_float2(y3x * w3.x - y3y * w3.y, y3x * w3.y + y3y * w3.x);
        }
        __syncthreads();
    }
}

// unpack both real spectra at bin k from packed FFT result (in LDS), reg out.
__device__ __forceinline__ void unpack_k(const float2* xs, int k,
                                         float& mx, float& my)
{
    const unsigned rk = __brev((unsigned)k) >> 22;
    const unsigned pk = ((rk & 0x155u) << 1) | ((rk & 0x2AAu) >> 1);
    const unsigned mI = (unsigned)(1024 - k) & 1023u;
    const unsigned rm = __brev(mI) >> 22;
    const unsigned pm = ((rm & 0x155u) << 1) | ((rm & 0x2AAu) >> 1);
    const float2 Zk = xs[SW(pk)];
    const float2 Zm = xs[SW(pm)];
    const float ar = Zk.x + Zm.x, ai = Zk.y - Zm.y;   // 2*X[k]
    const float br = Zk.y + Zm.y, bi = Zk.x - Zm.x;   // 2*Y[k]
    mx = fmaxf(0.5f * sqrtf(ar * ar + ai * ai), EPSV);
    my = fmaxf(0.5f * sqrtf(br * br + bi * bi), EPSV);
}

// ---------------------------------------------------------------------------
// Fused STFT + patch-partials, register-staged. Block = (pair p, batch b).
// Thread tid owns bins {tid, tid+256, tid+512}; s,t,g magnitudes meet in
// registers. part layout [b][g16][pair][3]: a patch's 8 pair-partials are 24
// contiguous floats for the topk kernel.
// ---------------------------------------------------------------------------
__global__ __launch_bounds__(256) void stft_pair_kernel(
    const float* __restrict__ s_in, const float* __restrict__ t_in,
    const float* __restrict__ g_in,
    float* __restrict__ part)
{
    __shared__ float2 xs[1024];
    __shared__ float2 tw[256];

    const int tid = threadIdx.x;
    const int p   = blockIdx.x;   // 0..512
    const int b   = blockIdx.y;   // 0..15

    const float* sp = s_in + (size_t)b * LEN;
    const float* tp = t_in + (size_t)b * LEN;
    const float* gp = g_in + (size_t)b * LEN;

    float2 w0;
    {   // tw[j] = exp(-2*pi*i*j/1024), j<256; keep own value for stage 0
        float sv, cv;
        sincosf(-6.283185307179586476925f * (float)tid * (1.0f / 1024.0f), &sv, &cv);
        w0 = make_float2(cv, sv);
        tw[SW(tid)] = w0;
    }

    const bool hasB  = (2 * p + 1) < NFRM;     // pair 512 has only frame 1024
    const bool fast  = (p >= 1) && (p <= 510); // all 3 windows fully in-bounds
    const int startA = 2 * p * HOP - PADW;
    const int startB = startA + HOP;

    float sA[3], tA[3], sB[3], tB[3];

    // FFT1: s + i*t at frame A
    if (fast) load_pack_fast(xs, sp, tp, startA, startA, tid);
    else      load_pack_edge(xs, sp, tp, startA, startA, tid);
    fft1024(xs, tw, w0, tid);
    #pragma unroll
    for (int it = 0; it < 3; ++it) {
        const int k = tid + 256 * it;
        sA[it] = 0.0f; tA[it] = 0.0f;
        if (k <= 512) unpack_k(xs, k, sA[it], tA[it]);
    }
    __syncthreads();   // xs reads done before next load overwrites

    // FFT2: s + i*t at frame B (runs for p=512 too; stats gated by hasB)
    if (fast) load_pack_fast(xs, sp, tp, startB, startB, tid);
    else      load_pack_edge(xs, sp, tp, startB, startB, tid);
    fft1024(xs, tw, w0, tid);
    #pragma unroll
    for (int it = 0; it < 3; ++it) {
        const int k = tid + 256 * it;
        sB[it] = 0.0f; tB[it] = 0.0f;
        if (k <= 512) unpack_k(xs, k, sB[it], tB[it]);
    }
    __syncthreads();

    // FFT3: g@A + i*g@B
    if (fast) load_pack_fast(xs, gp, gp, startA, startB, tid);
    else      load_pack_edge(xs, gp, gp, startA, startB, tid);
    fft1024(xs, tw, w0, tid);

    // stats per bin; A and B contributions fused into one reduce chain
    #pragma unroll
    for (int it = 0; it < 3; ++it) {
        const int k = tid + 256 * it;
        const bool valid = (k <= 512);
        float as = 0.0f, at = 0.0f, sq = 0.0f;
        if (valid) {
            float gA_, gB_;
            unpack_k(xs, k, gA_, gB_);
            as = fabsf(sA[it] - gA_);
            at = fabsf(tA[it] - gA_);
            sq = (sA[it] - tA[it]) * (sA[it] - tA[it]);
            if (hasB) {
                as += fabsf(sB[it] - gB_);
                at += fabsf(tB[it] - gB_);
                sq += (sB[it] - tB[it]) * (sB[it] - tB[it]);
            }
        }
        #pragma unroll
        for (int off = 8; off >= 1; off >>= 1) {
            as += __shfl_down(as, off);
            at += __shfl_down(at, off);
            sq += __shfl_down(sq, off);
        }
        if ((tid & 15) == 0 && valid) {
            const int g16 = k >> 4;            // 0..32, unique per (leader, it)
            float* slot = part + (((size_t)b * NPF + g16) * NPAIR + p) * 3;
            slot[0] = as; slot[1] = at; slot[2] = sq;
        }
    }
}

// ---------------------------------------------------------------------------
// Fused combine + top-k per batch row. 1024 threads, 1 block per row.
// Phase A: patch sums from part (24 contiguous floats per patch).
// Phase B: 8-bit MSB radix select (threshold T = TOPK-th largest key).
// Phase C: selected patch_loss sum; jax tie-break (lowest index at T).
// ---------------------------------------------------------------------------
__global__ __launch_bounds__(1024) void topk_kernel(
    const float* __restrict__ part,
    float* __restrict__ rowstats)  // [16][3] = {selected_sum, kgs_sum, pos_count}
{
    __shared__ unsigned ukey[NPATCH];
    __shared__ float    plv[NPATCH];
    __shared__ unsigned hist[256];
    __shared__ unsigned wtot[4];
    __shared__ int      tIdx[NPATCH];
    __shared__ int      tcnt;
    __shared__ unsigned selB, selHi;
    __shared__ float    red[3][16];

    const int tid = threadIdx.x;
    const int b   = blockIdx.x;

    // Phase A: combine pair partials -> kgs key + patch_loss, in LDS.
    float lsum = 0.0f, lpos = 0.0f;
    for (int p2 = tid; p2 < NPATCH; p2 += 1024) {
        const int fi = p2 / NPT;
        const int ti = p2 - fi * NPT;
        const float* base = part + (((size_t)b * NPF + fi) * NPAIR + ti * 8) * 3;
        float a = 0.0f, t3 = 0.0f, q = 0.0f;
        #pragma unroll
        for (int u = 0; u < 8; ++u) {
            if (ti * 8 + u < NPAIR) {
                a  += base[u * 3 + 0];
                t3 += base[u * 3 + 1];
                q  += base[u * 3 + 2];
            }
        }
        const float kg = (a - t3) * (1.0f / 256.0f);
        lsum += kg;
        lpos += (kg > 0.0f) ? 1.0f : 0.0f;
        plv[p2] = q * (1.0f / 256.0f);
        unsigned u32 = __float_as_uint(kg);
        ukey[p2] = (u32 & 0x80000000u) ? ~u32 : (u32 | 0x80000000u);
    }
    if (tid == 0) tcnt = 0;
    __syncthreads();

    // Phase B: radix select.
    unsigned prefix = 0;
    int rem = TOPK;
    #pragma unroll
    for (int pass = 0; pass < 4; ++pass) {
        const int shift = 24 - 8 * pass;
        const unsigned himask = (pass == 0) ? 0u : (0xFFFFFFFFu << (shift + 8));

        if (tid < 256) hist[tid] = 0;
        __syncthreads();
        for (int i = tid; i < NPATCH; i += 1024) {
            unsigned u = ukey[i];
            if ((u & himask) == (prefix & himask))
                atomicAdd(&hist[(u >> shift) & 255u], 1u);
        }
        __syncthreads();

        if (tid < 256) {
            const unsigned h = hist[tid];
            unsigned v = h;
            const int lane = tid & 63;
            const int w    = tid >> 6;
            #pragma unroll
            for (int off = 1; off < 64; off <<= 1) {
                unsigned tval = __shfl_down(v, off);
                if (lane + off < 64) v += tval;
            }
            if (lane == 0) wtot[w] = v;
            __syncthreads();
            unsigned addv = 0;
            for (int w2 = w + 1; w2 < 4; ++w2) addv += wtot[w2];
            v += addv;                    // suffix sum over bins >= tid
            const unsigned hi = v - h;    // suffix sum over bins >  tid
            if (v >= (unsigned)rem && hi < (unsigned)rem) { selB = (unsigned)tid; selHi = hi; }
        } else {
            __syncthreads();              // match the barrier inside the guard
        }
        __syncthreads();
        prefix |= (selB << shift);
        rem -= (int)selHi;
        __syncthreads();                  // protect selB/hist before next pass
    }

    // Phase C: selected sums.
    const unsigned T = prefix;
    float ssum = 0.0f;
    for (int i = tid; i < NPATCH; i += 1024) {
        unsigned u = ukey[i];
        if (u > T) {
            ssum += plv[i];
        } else if (u == T) {
            int j = atomicAdd(&tcnt, 1);
            tIdx[j] = i;
        }
    }
    __syncthreads();
    const int m = tcnt;
    if (m == rem) {
        for (int j = tid; j < m; j += 1024) ssum += plv[tIdx[j]];
    } else {
        for (int j = tid; j < m; j += 1024) {
            const int i = tIdx[j];
            int rank = 0;
            for (int q = 0; q < m; ++q) rank += (tIdx[q] < i) ? 1 : 0;
            if (rank < rem) ssum += plv[i];
        }
    }

    #pragma unroll
    for (int off = 32; off > 0; off >>= 1) {
        ssum += __shfl_down(ssum, off);
        lsum += __shfl_down(lsum, off);
        lpos += __shfl_down(lpos, off);
    }
    if ((tid & 63) == 0) {
        const int wv = tid >> 6;
        red[0][wv] = ssum; red[1][wv] = lsum; red[2][wv] = lpos;
    }
    __syncthreads();
    if (tid == 0) {
        float a = 0.0f, c = 0.0f, d = 0.0f;
        #pragma unroll
        for (int i = 0; i < 16; ++i) { a += red[0][i]; c += red[1][i]; d += red[2][i]; }
        rowstats[b * 3 + 0] = a;
        rowstats[b * 3 + 1] = c;
        rowstats[b * 3 + 2] = d;
    }
}

// ---------------------------------------------------------------------------
// Final reduction over 16 rows -> 4 scalars.
// ---------------------------------------------------------------------------
__global__ __launch_bounds__(64) void final_kernel(
    const float* __restrict__ rowstats,
    float* __restrict__ out)
{
    const int tid = threadIdx.x;
    float loss = 0.0f, ks = 0.0f, pc = 0.0f;
    if (tid < BATCH) {
        loss = rowstats[tid * 3 + 0] * (1.0f / (float)TOPK);
        ks   = rowstats[tid * 3 + 1];
        pc   = rowstats[tid * 3 + 2];
    }
    #pragma unroll
    for (int off = 32; off > 0; off >>= 1) {
        loss += __shfl_down(loss, off);
        ks   += __shfl_down(ks, off);
        pc   += __shfl_down(pc, off);
    }
    if (tid == 0) {
        out[0] = loss * (1.0f / (float)BATCH);
        out[1] = (float)TOPK / (float)NPATCH;
        out[2] = ks * (1.0f / ((float)BATCH * (float)NPATCH));
        out[3] = pc * (1.0f / ((float)BATCH * (float)NPATCH));
    }
}

// ---------------------------------------------------------------------------
extern "C" void kernel_launch(void* const* d_in, const int* in_sizes, int n_in,
                              void* d_out, int out_size, void* d_ws, size_t ws_size,
                              hipStream_t stream)
{
    const float* s_in = (const float*)d_in[0];
    const float* t_in = (const float*)d_in[1];
    const float* g_in = (const float*)d_in[2];
    float* out = (float*)d_out;

    float* part = (float*)d_ws;                               // 16*33*513*3 floats
    float* rowstats = part + (size_t)BATCH * NPF * NPAIR * 3;

    dim3 g1(NPAIR, BATCH);
    stft_pair_kernel<<<g1, 256, 0, stream>>>(s_in, t_in, g_in, part);

    topk_kernel<<<BATCH, 1024, 0, stream>>>(part, rowstats);

    final_kernel<<<1, 64, 0, stream>>>(rowstats, out);
}